// Round 1
// baseline (1275.016 us; speedup 1.0000x reference)
//
#include <hip/hip_runtime.h>
#include <hip/hip_bf16.h>

typedef __attribute__((ext_vector_type(8))) short short8;
typedef __attribute__((ext_vector_type(4))) float f32x4;

#define NB    4      // n's per block
#define F1    512    // stage-1 contraction (4E)
#define BK    64     // stage-1 K chunk
#define LDX   72     // 64 + 8 bf16 pad (keeps 16B align, 2-way-max bank alias)
#define XCP   264    // xcat row: 256 + 8 pad

// ---------------- prep: transpose + bf16-cast weights into workspace ----------
__global__ __launch_bounds__(256) void prep_weights(
    const float* __restrict__ W1, const float* __restrict__ W2,
    __hip_bfloat16* __restrict__ W1T, __hip_bfloat16* __restrict__ W2T)
{
    int t = blockIdx.x * 256 + threadIdx.x;
    if (t < 128 * 512) {                 // W1T[e][f] = W1[f][e]
        int e = t >> 9, f = t & 511;
        W1T[t] = __float2bfloat16(W1[f * 128 + e]);
    } else {
        int u = t - 128 * 512;           // W2T[e][f2] = W2[f2][e]
        int e = u >> 8, f = u & 255;
        W2T[u] = __float2bfloat16(W2[f * 128 + e]);
    }
}

// ---------------- fused main kernel ----------------
__global__ __launch_bounds__(256) void fused_kernel(
    const float* __restrict__ msg,     // [N][32][384]
    const float* __restrict__ e_repr,  // [N][32][128]
    const float* __restrict__ alpha,   // [N][32]
    const float* __restrict__ curr,    // [N][32][128]
    const float* __restrict__ b1,      // [128]
    const float* __restrict__ b2,      // [128]
    const __hip_bfloat16* __restrict__ W1T, // [128][512]
    const __hip_bfloat16* __restrict__ W2T, // [128][256]
    float* __restrict__ out)           // [N][128]
{
    __shared__ __hip_bfloat16 Xs[128][LDX];
    __shared__ __hip_bfloat16 Ws[128][LDX];
    __shared__ __hip_bfloat16 xcat[16][XCP]; // rows 0..3 valid: [ce(128) | nei(128)]
    __shared__ float aS[NB * 32];

    const int t    = threadIdx.x;
    const int n0   = blockIdx.x * NB;
    const int w    = t >> 6;        // wave id == local n
    const int lane = t & 63;
    const int qd   = lane >> 4;
    const int lc   = lane & 15;

    // ce rows of xcat (independent of main loop)
    {
        int e = (t & 63) * 2;
        const float2 v = *(const float2*)(curr + ((size_t)(n0 + w) * 32) * 128 + e);
        xcat[w][e]     = __float2bfloat16(v.x);
        xcat[w][e + 1] = __float2bfloat16(v.y);
    }
    if (t < NB * 32) aS[t] = alpha[n0 * 32 + t];

    f32x4 acc[2][8];
    #pragma unroll
    for (int mi = 0; mi < 2; mi++)
        #pragma unroll
        for (int ni = 0; ni < 8; ni++) acc[mi][ni] = (f32x4){0.f, 0.f, 0.f, 0.f};

    const int xr  = t >> 4;   // X-load: row group lane
    const int xc4 = t & 15;   // X-load: float4 col
    const int wr  = t >> 1;   // W-load: row
    const int wsg = t & 1;    // W-load: segment

    for (int kk = 0; kk < F1; kk += BK) {
        __syncthreads();
        // ---- X tile: 128 rows x 64 fp32 -> bf16 LDS ----
        const float* src; int rs;
        if (kk < 384) { src = msg    + (size_t)n0 * 32 * 384 + kk;         rs = 384; }
        else          { src = e_repr + (size_t)n0 * 32 * 128 + (kk - 384); rs = 128; }
        #pragma unroll
        for (int p = 0; p < 8; p++) {
            int row = p * 16 + xr;
            float4 v = *(const float4*)(src + (size_t)row * rs + xc4 * 4);
            __hip_bfloat16 c0 = __float2bfloat16(v.x);
            __hip_bfloat16 c1 = __float2bfloat16(v.y);
            __hip_bfloat16 c2 = __float2bfloat16(v.z);
            __hip_bfloat16 c3 = __float2bfloat16(v.w);
            ushort4 u;
            u.x = *(unsigned short*)&c0; u.y = *(unsigned short*)&c1;
            u.z = *(unsigned short*)&c2; u.w = *(unsigned short*)&c3;
            *(ushort4*)&Xs[row][xc4 * 4] = u;
        }
        // ---- W1T tile: 128 rows x 64 bf16 (already bf16, straight copy) ----
        #pragma unroll
        for (int i = 0; i < 4; i++) {
            int col = wsg * 32 + i * 8;
            float4 v = *(const float4*)(W1T + (size_t)wr * 512 + kk + col);
            *(float4*)&Ws[wr][col] = v;
        }
        __syncthreads();
        // ---- MFMA: wave w computes rows [w*32, w*32+32) x all 128 cols ----
        #pragma unroll
        for (int ki = 0; ki < 2; ki++) {
            short8 a0 = *(const short8*)&Xs[w * 32 + lc][ki * 32 + qd * 8];
            short8 a1 = *(const short8*)&Xs[w * 32 + 16 + lc][ki * 32 + qd * 8];
            #pragma unroll
            for (int ni = 0; ni < 8; ni++) {
                short8 b = *(const short8*)&Ws[ni * 16 + lc][ki * 32 + qd * 8];
                acc[0][ni] = __builtin_amdgcn_mfma_f32_16x16x32_bf16(a0, b, acc[0][ni], 0, 0, 0);
                acc[1][ni] = __builtin_amdgcn_mfma_f32_16x16x32_bf16(a1, b, acc[1][ni], 0, 0, 0);
            }
        }
    }

    // ---- fused epilogue 1: relu(+b1), alpha-weighted sum over the 32 k rows ----
    // acc[mi][ni] reg r holds H[k = mi*16 + qd*4 + r][col = ni*16 + lc] for n = n0+w
    #pragma unroll
    for (int ni = 0; ni < 8; ni++) {
        float bias = b1[ni * 16 + lc];
        float s = 0.f;
        #pragma unroll
        for (int mi = 0; mi < 2; mi++)
            #pragma unroll
            for (int r = 0; r < 4; r++) {
                int k = mi * 16 + qd * 4 + r;
                float h = acc[mi][ni][r] + bias;
                h = h > 0.f ? h : 0.f;
                s += h * aS[w * 32 + k];
            }
        s += __shfl_xor(s, 16, 64);   // reduce across quads
        s += __shfl_xor(s, 32, 64);
        if (lane < 16) xcat[w][128 + ni * 16 + lc] = __float2bfloat16(s);
    }
    __syncthreads();

    // ---- fused stage 2: emb = relu(xcat @ W2 + b2); M=16 padded, rows 0..3 valid ----
    f32x4 acc2[2];
    acc2[0] = (f32x4){0.f, 0.f, 0.f, 0.f};
    acc2[1] = (f32x4){0.f, 0.f, 0.f, 0.f};
    #pragma unroll
    for (int k2 = 0; k2 < 8; k2++) {
        short8 a = *(const short8*)&xcat[lc][k2 * 32 + qd * 8];
        #pragma unroll
        for (int t2 = 0; t2 < 2; t2++) {
            int ct = w * 2 + t2;
            short8 b = *(const short8*)(W2T + (size_t)(ct * 16 + lc) * 256 + k2 * 32 + qd * 8);
            acc2[t2] = __builtin_amdgcn_mfma_f32_16x16x32_bf16(a, b, acc2[t2], 0, 0, 0);
        }
    }
    if (lane < 16) {  // qd==0 holds D rows 0..3 (= local n)
        #pragma unroll
        for (int t2 = 0; t2 < 2; t2++) {
            int col = (w * 2 + t2) * 16 + lc;
            float bias = b2[col];
            #pragma unroll
            for (int r = 0; r < 4; r++) {
                float v = acc2[t2][r] + bias;
                v = v > 0.f ? v : 0.f;
                out[(size_t)(n0 + r) * 128 + col] = v;
            }
        }
    }
}

extern "C" void kernel_launch(void* const* d_in, const int* in_sizes, int n_in,
                              void* d_out, int out_size, void* d_ws, size_t ws_size,
                              hipStream_t stream) {
    const float* msg    = (const float*)d_in[0];
    const float* e_repr = (const float*)d_in[1];
    const float* alpha  = (const float*)d_in[2];
    const float* curr   = (const float*)d_in[3];
    const float* W1     = (const float*)d_in[4];
    const float* b1     = (const float*)d_in[5];
    const float* W2     = (const float*)d_in[6];
    const float* b2     = (const float*)d_in[7];
    float* out = (float*)d_out;

    __hip_bfloat16* W1T = (__hip_bfloat16*)d_ws;                       // 128*512 bf16
    __hip_bfloat16* W2T = (__hip_bfloat16*)((char*)d_ws + 128*512*2);  // 128*256 bf16

    prep_weights<<<(128*512 + 128*256) / 256, 256, 0, stream>>>(W1, W2, W1T, W2T);
    fused_kernel<<<16384 / NB, 256, 0, stream>>>(msg, e_repr, alpha, curr, b1, b2,
                                                 W1T, W2T, out);
}